// Round 9
// baseline (161.689 us; speedup 1.0000x reference)
//
#include <hip/hip_runtime.h>
#include <stdint.h>

// PureOrthoPhasor: out = x + LN-epilogue GEMM( scan( GEMM(x,Wv), phases ), Wo )
// D=1024, L=4096, B=4, M = B*L = 16384.
// R9: traffic elimination (GEMM schedule family exhausted: R3/R5/R6/R8 all
// 46-51us / 26-28% MfmaUtil).
//  - gemm1 (MODE0) stages A straight from f32 x: p1 issues 8 dwordx4 reg-loads
//    (compiler-counted waits), p3 converts (f2bf RNE, bit-identical to prep)
//    and ds_write_b128's into the parity-free A slots. Kills the 96MB x-prep.
//  - gemm2 (MODE1, unchanged R8 GLL path) reads residual as f32 x (L3-warm);
//    xb eliminated.
//  - prep = Wv convert + Wo row prep only (12MB).
// Ledger (MODE0): A(p^1) slots free from tile start (last read p4(ks-1) before
// its barrier); ds_writes drained by p3's lgkm(0) + p3/p4 barriers before the
// p1(ks+1) readers; B GLLs forced by p4-end vmcnt(0), 2 phases after issue.

#define D_DIM 1024
#define L_DIM 4096
#define B_DIM 4
#define M_DIM (B_DIM * L_DIM)
#define CHUNK 64
#define NCH (L_DIM / CHUNK)
#define NT 16  // K steps (1024/64)

typedef __attribute__((ext_vector_type(8))) short short8;
typedef __attribute__((ext_vector_type(4))) float f32x4;

__device__ __forceinline__ float bf2f(uint32_t h) {
  union { uint32_t u; float f; } x; x.u = h << 16; return x.f;
}
__device__ __forceinline__ uint16_t f2bf(float f) {
  union { float f; uint32_t u; } x; x.f = f;
  uint32_t u = x.u;
  u += 0x7fffu + ((u >> 16) & 1u);   // round-to-nearest-even
  return (uint16_t)(u >> 16);
}
__device__ __forceinline__ uint32_t pk2(float lo, float hi) {
  return (uint32_t)f2bf(lo) | ((uint32_t)f2bf(hi) << 16);
}

// ---------- prep: convert Wv, build Wo'/u/vb (x conversion eliminated) ----------
__global__ void k_prep(const float* __restrict__ Wv, const float* __restrict__ Wo,
                       const float* __restrict__ g, const float* __restrict__ bln,
                       const float* __restrict__ bo, uint16_t* __restrict__ wv,
                       uint16_t* __restrict__ wob, float* __restrict__ u,
                       float* __restrict__ vb) {
  int blk = blockIdx.x;
  int tid = threadIdx.x;
  if (blk < 512) {
    int i = (blk * 256 + tid) * 8;
    float4 a = *(const float4*)(Wv + i);
    float4 b = *(const float4*)(Wv + i + 4);
    ushort4 o0 = { f2bf(a.x), f2bf(a.y), f2bf(a.z), f2bf(a.w) };
    ushort4 o1 = { f2bf(b.x), f2bf(b.y), f2bf(b.z), f2bf(b.w) };
    *(ushort4*)(wv + i) = o0;
    *(ushort4*)(wv + i + 4) = o1;
    return;
  }
  int e = blk - 512;
  int d = tid * 4;
  float4 w  = *(const float4*)(Wo + (size_t)e * D_DIM + d);
  float4 gg = *(const float4*)(g + d);
  float4 bb = *(const float4*)(bln + d);
  float gw0 = gg.x * w.x, gw1 = gg.y * w.y, gw2 = gg.z * w.z, gw3 = gg.w * w.w;
  ushort4 o = { f2bf(gw0), f2bf(gw1), f2bf(gw2), f2bf(gw3) };
  *(ushort4*)(wob + (size_t)e * D_DIM + d) = o;
  float su = gw0 + gw1 + gw2 + gw3;
  float sv = bb.x * w.x + bb.y * w.y + bb.z * w.z + bb.w * w.w;
#pragma unroll
  for (int off = 32; off > 0; off >>= 1) {
    su += __shfl_down(su, off);
    sv += __shfl_down(sv, off);
  }
  __shared__ float s1[4], s2[4];
  int wid = tid >> 6, lane = tid & 63;
  if (lane == 0) { s1[wid] = su; s2[wid] = sv; }
  __syncthreads();
  if (tid == 0) {
    u[e]  = s1[0] + s1[1] + s1[2] + s1[3];
    vb[e] = s2[0] + s2[1] + s2[2] + s2[3] + bo[e];
  }
}

// ---------- 256x256 fine-phase bf16 MFMA GEMM ----------
// C[m][n] = sum_k A[m][k] * W[n][k].  8 waves = 2(M) x 4(N); wave owns 128x64.
// MODE 0: A staged from f32 Af32 (reg-load + cvt + ds_write); out(bf16) = C+p0[n]
// MODE 1: A staged via global_load_lds from bf16 A (R8 path);
//         out(f32) = inv[m]*C - inv[m]*mu[m]*p0[n] + p1[n] + xres[m][n] (f32)
template <int MODE>
__global__ __launch_bounds__(512, 2) void k_gemm(
    const uint16_t* __restrict__ A, const uint16_t* __restrict__ W,
    void* __restrict__ outp,
    const float* __restrict__ p0, const float* __restrict__ p1,
    const float* __restrict__ mu, const float* __restrict__ inv,
    const float* __restrict__ xres, const float* __restrict__ Af32) {
  __shared__ char lds[8 * 16384];   // slots [par*4 + {0:A0,1:A1,2:B0,3:B1}]
  const int tid = threadIdx.x;
  const int lane = tid & 63;
  const int wid = tid >> 6;           // 0..7
  const int wm = wid >> 2;            // 0..1
  const int wn = wid & 3;             // 0..3

  // XCD swizzle: 256 blocks, 8 XCDs, 32 blocks/XCD; bn fastest within chunk.
  const int idx = blockIdx.x;
  const int bm = (idx & 7) * 8 + ((idx >> 3) >> 2);  // 0..63
  const int bn = (idx >> 3) & 3;                     // 0..3

  // GLL staging geometry (MODE 1 A, both modes B)
  const int srow = tid >> 3;               // 0..63
  const int scb  = (tid & 7) * 16;         // 0..112
  const int scbs = scb ^ ((srow & 7) << 4);

  // reg-stage geometry (MODE 0 A): thread -> row (0..127), 16-f32 col chunk
  const int arow = tid >> 2;               // 0..127
  const int acf  = (tid & 3) * 16;         // f32 col within 64-col K-tile
  const int acb  = (tid & 3) * 32;         // bf16 col-byte
  const int aswz = (arow & 7) << 4;

#define GLL(SRC, DST)                                                            \
  __builtin_amdgcn_global_load_lds((const __attribute__((address_space(1))) void*)(SRC), \
                                   (__attribute__((address_space(3))) void*)(DST), 16, 0, 0)

#define STAGE_A(KS, HA)                                                          \
  do {                                                                           \
    char* _d = lds + ((((KS)&1) * 4 + (HA)) << 14) + tid * 16;                   \
    const char* _s = (const char*)A +                                            \
        (size_t)(bm * 256 + (HA) * 128 + srow) * 2048 + (KS) * 128 + scbs;       \
    GLL(_s, _d);                                                                 \
    GLL(_s + (size_t)64 * 2048, _d + 8192);                                      \
  } while (0)

#define STAGE_B(KS, HB)                                                          \
  do {                                                                           \
    char* _d = lds + ((((KS)&1) * 4 + 2 + (HB)) << 14) + tid * 16;               \
    const char* _s = (const char*)W +                                            \
        (size_t)(bn * 256 + (HB) * 128 + srow) * 2048 + (KS) * 128 + scbs;       \
    GLL(_s, _d);                                                                 \
    GLL(_s + (size_t)64 * 2048, _d + 8192);                                      \
  } while (0)

// MODE0: issue 4 dwordx4 f32 loads for half HA of tile KS into R[0..3]
#define A_ISSUE(KS, HA, R)                                                       \
  do {                                                                           \
    const float* _s = Af32 + (size_t)(bm * 256 + (HA) * 128 + arow) * D_DIM +    \
                      (KS) * 64 + acf;                                           \
    R[0] = *(const float4*)(_s);      R[1] = *(const float4*)(_s + 4);           \
    R[2] = *(const float4*)(_s + 8);  R[3] = *(const float4*)(_s + 12);          \
  } while (0)

// MODE0: convert+pack R0 (half 0) / R1 (half 1) and ds_write to parity KSP slots
#define CVT_WRITE(KSP, R0, R1)                                                   \
  do {                                                                           \
    char* _d0 = lds + (((KSP) * 4 + 0) << 14) + arow * 128;                      \
    char* _d1 = lds + (((KSP) * 4 + 1) << 14) + arow * 128;                      \
    int4 _g;                                                                     \
    _g.x = pk2(R0[0].x, R0[0].y); _g.y = pk2(R0[0].z, R0[0].w);                  \
    _g.z = pk2(R0[1].x, R0[1].y); _g.w = pk2(R0[1].z, R0[1].w);                  \
    *(int4*)(_d0 + (acb ^ aswz)) = _g;                                           \
    _g.x = pk2(R0[2].x, R0[2].y); _g.y = pk2(R0[2].z, R0[2].w);                  \
    _g.z = pk2(R0[3].x, R0[3].y); _g.w = pk2(R0[3].z, R0[3].w);                  \
    *(int4*)(_d0 + ((acb + 16) ^ aswz)) = _g;                                    \
    _g.x = pk2(R1[0].x, R1[0].y); _g.y = pk2(R1[0].z, R1[0].w);                  \
    _g.z = pk2(R1[1].x, R1[1].y); _g.w = pk2(R1[1].z, R1[1].w);                  \
    *(int4*)(_d1 + (acb ^ aswz)) = _g;                                           \
    _g.x = pk2(R1[2].x, R1[2].y); _g.y = pk2(R1[2].z, R1[2].w);                  \
    _g.z = pk2(R1[3].x, R1[3].y); _g.w = pk2(R1[3].z, R1[3].w);                  \
    *(int4*)(_d1 + ((acb + 16) ^ aswz)) = _g;                                    \
  } while (0)

  // swizzled ds_read fragment loads
  const int axor = (lane & 7) << 4;
  const int afr  = lane & 15;
  const int acol = (lane >> 4) * 16;

#define LD_A(PAR, I, KK)                                                         \
  (*(const short8*)(lds + (((PAR) * 4 + wm) << 14) + ((I) * 16 + afr) * 128 +    \
                    (((KK) * 64 + acol) ^ axor)))
#define LD_B(PAR, J, KK)                                                         \
  (*(const short8*)(lds + (((PAR) * 4 + 2 + (wn >> 1)) << 14) +                  \
                    ((wn & 1) * 64 + (J) * 16 + afr) * 128 +                     \
                    (((KK) * 64 + acol) ^ axor)))

#define MFMA(AV, BV, CV) __builtin_amdgcn_mfma_f32_16x16x32_bf16(AV, BV, CV, 0, 0, 0)
#define SB0() __builtin_amdgcn_sched_barrier(0)

  f32x4 acc[8][4];
#pragma unroll
  for (int i = 0; i < 8; ++i)
#pragma unroll
    for (int j = 0; j < 4; ++j)
      acc[i][j] = (f32x4){0.f, 0.f, 0.f, 0.f};

  // prologue: tile 0 into parity-0 slots
  if constexpr (MODE == 0) {
    float4 q0[4], q1[4];
    A_ISSUE(0, 0, q0); A_ISSUE(0, 1, q1);
    STAGE_B(0, 0); STAGE_B(0, 1);
    CVT_WRITE(0, q0, q1);             // compiler inserts waits for q0/q1
    asm volatile("s_waitcnt vmcnt(0)" ::: "memory");   // B GLLs landed
    asm volatile("s_waitcnt lgkmcnt(0)" ::: "memory"); // ds_writes drained
  } else {
    STAGE_A(0, 0); STAGE_A(0, 1);
    STAGE_B(0, 0); STAGE_B(0, 1);
    asm volatile("s_waitcnt vmcnt(0)" ::: "memory");
  }
  __builtin_amdgcn_s_barrier();

  for (int ks = 0; ks < NT; ++ks) {
    const int par = ks & 1;
    short8 Af0, Af1, Af2, Af3, Bf0, Bf1, Bf2, Bf3;
    float4 rA0[4], rA1[4];

    // ======== p1: read B(kk0)+A(m0-3,kk0); issue/stage A(ks+1); MFMA quad0
    Bf0 = LD_B(par, 0, 0); Bf1 = LD_B(par, 1, 0); Bf2 = LD_B(par, 2, 0); Bf3 = LD_B(par, 3, 0);
    Af0 = LD_A(par, 0, 0); Af1 = LD_A(par, 1, 0); Af2 = LD_A(par, 2, 0); Af3 = LD_A(par, 3, 0);
    SB0();
    if (ks + 1 < NT) {
      if constexpr (MODE == 0) { A_ISSUE(ks + 1, 0, rA0); A_ISSUE(ks + 1, 1, rA1); }
      else                     { STAGE_A(ks + 1, 0); STAGE_A(ks + 1, 1); }
    }
    __builtin_amdgcn_s_barrier();
    asm volatile("s_waitcnt lgkmcnt(0)" ::: "memory");
    SB0();
    __builtin_amdgcn_s_setprio(1);
#pragma unroll
    for (int j = 0; j < 4; ++j) {
      const short8 bj = (j == 0) ? Bf0 : (j == 1) ? Bf1 : (j == 2) ? Bf2 : Bf3;
      acc[0][j] = MFMA(Af0, bj, acc[0][j]);
      acc[1][j] = MFMA(Af1, bj, acc[1][j]);
      acc[2][j] = MFMA(Af2, bj, acc[2][j]);
      acc[3][j] = MFMA(Af3, bj, acc[3][j]);
    }
    __builtin_amdgcn_s_setprio(0);
    __builtin_amdgcn_s_barrier();

    // ======== p2: read A(m4-7,kk0); stage B(ks+1); MFMA quad1 (B regs reused)
    Af0 = LD_A(par, 4, 0); Af1 = LD_A(par, 5, 0); Af2 = LD_A(par, 6, 0); Af3 = LD_A(par, 7, 0);
    SB0();
    if (ks + 1 < NT) { STAGE_B(ks + 1, 0); STAGE_B(ks + 1, 1); }
    __builtin_amdgcn_s_barrier();
    asm volatile("s_waitcnt lgkmcnt(0)" ::: "memory");
    SB0();
    __builtin_amdgcn_s_setprio(1);
#pragma unroll
    for (int j = 0; j < 4; ++j) {
      const short8 bj = (j == 0) ? Bf0 : (j == 1) ? Bf1 : (j == 2) ? Bf2 : Bf3;
      acc[4][j] = MFMA(Af0, bj, acc[4][j]);
      acc[5][j] = MFMA(Af1, bj, acc[5][j]);
      acc[6][j] = MFMA(Af2, bj, acc[6][j]);
      acc[7][j] = MFMA(Af3, bj, acc[7][j]);
    }
    __builtin_amdgcn_s_setprio(0);
    __builtin_amdgcn_s_barrier();

    // ======== p3: read B(kk1)+A(m0-3,kk1); MODE0: cvt+ds_write A(ks+1); MFMA quad2
    Bf0 = LD_B(par, 0, 1); Bf1 = LD_B(par, 1, 1); Bf2 = LD_B(par, 2, 1); Bf3 = LD_B(par, 3, 1);
    Af0 = LD_A(par, 0, 1); Af1 = LD_A(par, 1, 1); Af2 = LD_A(par, 2, 1); Af3 = LD_A(par, 3, 1);
    SB0();
    if constexpr (MODE == 0) {
      if (ks + 1 < NT) CVT_WRITE((ks + 1) & 1, rA0, rA1);
    }
    __builtin_amdgcn_s_barrier();
    asm volatile("s_waitcnt lgkmcnt(0)" ::: "memory");
    SB0();
    __builtin_amdgcn_s_setprio(1);
#pragma unroll
    for (int j = 0; j < 4; ++j) {
      const short8 bj = (j == 0) ? Bf0 : (j == 1) ? Bf1 : (j == 2) ? Bf2 : Bf3;
      acc[0][j] = MFMA(Af0, bj, acc[0][j]);
      acc[1][j] = MFMA(Af1, bj, acc[1][j]);
      acc[2][j] = MFMA(Af2, bj, acc[2][j]);
      acc[3][j] = MFMA(Af3, bj, acc[3][j]);
    }
    __builtin_amdgcn_s_setprio(0);
    if constexpr (MODE == 1) {
      asm volatile("s_waitcnt vmcnt(4)" ::: "memory");   // forces A GLLs (ks+1)
    }
    __builtin_amdgcn_s_barrier();

    // ======== p4: read A(m4-7,kk1); MFMA quad3; vmcnt(0) [B(ks+1), 2 phases old]
    Af0 = LD_A(par, 4, 1); Af1 = LD_A(par, 5, 1); Af2 = LD_A(par, 6, 1); Af3 = LD_A(par, 7, 1);
    SB0();
    __builtin_amdgcn_s_barrier();
    asm volatile("s_waitcnt lgkmcnt(0)" ::: "memory");
    SB0();
    __builtin_amdgcn_s_setprio(1);
#pragma unroll
    for (int j = 0; j < 4; ++j) {
      const short8 bj = (j == 0) ? Bf0 : (j == 1) ? Bf1 : (j == 2) ? Bf2 : Bf3;
      acc[4][j] = MFMA(Af0, bj, acc[4][j]);
      acc[5][j] = MFMA(Af1, bj, acc[5][j]);
      acc[6][j] = MFMA(Af2, bj, acc[6][j]);
      acc[7][j] = MFMA(Af3, bj, acc[7][j]);
    }
    __builtin_amdgcn_s_setprio(0);
    asm volatile("s_waitcnt vmcnt(0)" ::: "memory");
    __builtin_amdgcn_s_barrier();
  }

  // D layout per frag: col = lane&15, row = (lane>>4)*4 + reg
  if (MODE == 0) {
    // Repack through LDS -> fully-coalesced 16B bf16 stores.
    uint16_t* outv = (uint16_t*)outp;
    __syncthreads();
#pragma unroll
    for (int i = 0; i < 8; ++i)
#pragma unroll
      for (int r = 0; r < 4; ++r) {
        int row = wm * 128 + i * 16 + (lane >> 4) * 4 + r;
#pragma unroll
        for (int j = 0; j < 4; ++j) {
          int ncol = wn * 64 + j * 16 + (lane & 15);
          float v = acc[i][j][r] + p0[bn * 256 + ncol];
          *(uint16_t*)(lds + row * 512 + ((ncol * 2) ^ ((row & 7) << 4))) = f2bf(v);
        }
      }
    __syncthreads();
    {
      int row = tid >> 1, half = tid & 1;
      uint16_t* gdst = outv + (size_t)(bm * 256 + row) * D_DIM + bn * 256 + half * 128;
#pragma unroll
      for (int s = 0; s < 16; ++s) {
        short8 v = *(const short8*)(lds + row * 512 +
                                    ((half * 256 + s * 16) ^ ((row & 7) << 4)));
        *(short8*)(gdst + s * 8) = v;
      }
    }
  } else {
    float* outf = (float*)outp;
#pragma unroll
    for (int i = 0; i < 8; ++i)
#pragma unroll
      for (int r = 0; r < 4; ++r) {
        int m = bm * 256 + wm * 128 + i * 16 + (lane >> 4) * 4 + r;
        float im = inv[m], mm = mu[m];
#pragma unroll
        for (int j = 0; j < 4; ++j) {
          int n = bn * 256 + wn * 64 + j * 16 + (lane & 15);
          outf[(size_t)m * D_DIM + n] =
              im * acc[i][j][r] - im * mm * p0[n] + p1[n] +
              xres[(size_t)m * D_DIM + n];
        }
      }
  }
#undef GLL
#undef STAGE_A
#undef STAGE_B
#undef A_ISSUE
#undef CVT_WRITE
#undef LD_A
#undef LD_B
#undef MFMA
#undef SB0
}

// ---------- pass A: per-chunk partial sums of value*cos / value*sin ----------
__global__ void k_passA(const uint16_t* __restrict__ value, const float* __restrict__ phases,
                        float* __restrict__ pr, float* __restrict__ pi) {
  int d0 = blockIdx.x * 512 + threadIdx.x * 2;
  int c = blockIdx.y, b = blockIdx.z;
  const uint16_t* vp = value + ((size_t)(b * L_DIM + c * CHUNK)) * D_DIM + d0;
  const float* pp = phases + (size_t)(c * CHUNK) * D_DIM + d0;
  float sr0 = 0, si0 = 0, sr1 = 0, si1 = 0;
#pragma unroll 4
  for (int l = 0; l < CHUNK; ++l) {
    uint32_t vv = *(const uint32_t*)vp; vp += D_DIM;
    float2 ph = *(const float2*)pp; pp += D_DIM;
    float v0 = bf2f(vv & 0xffffu), v1 = bf2f(vv >> 16);
    float s0, c0, s1, c1;
    __sincosf(ph.x, &s0, &c0);
    __sincosf(ph.y, &s1, &c1);
    sr0 += v0 * c0; si0 += v0 * s0;
    sr1 += v1 * c1; si1 += v1 * s1;
  }
  size_t o = ((size_t)b * NCH + c) * D_DIM + d0;
  *(float2*)(pr + o) = make_float2(sr0, sr1);
  *(float2*)(pi + o) = make_float2(si0, si1);
}

// ---------- pass B: in-place exclusive scan of the NCH chunk partials ----------
__global__ void k_passB(float* __restrict__ pr, float* __restrict__ pi) {
  int d = blockIdx.x * 256 + threadIdx.x;
  int b = blockIdx.y;
  size_t base = (size_t)b * NCH * D_DIM + d;
  float r[NCH], im[NCH];
#pragma unroll
  for (int c = 0; c < NCH; ++c) r[c] = pr[base + (size_t)c * D_DIM];
#pragma unroll
  for (int c = 0; c < NCH; ++c) im[c] = pi[base + (size_t)c * D_DIM];
  float rr = 0, ri = 0;
#pragma unroll
  for (int c = 0; c < NCH; ++c) {
    float t = r[c]; r[c] = rr; rr += t;
    t = im[c]; im[c] = ri; ri += t;
  }
#pragma unroll
  for (int c = 0; c < NCH; ++c) pr[base + (size_t)c * D_DIM] = r[c];
#pragma unroll
  for (int c = 0; c < NCH; ++c) pi[base + (size_t)c * D_DIM] = im[c];
}

// ---------- pass C: replay chunk with offset, write retrieved (bf16, IN-PLACE) ----------
__global__ void k_passC(const uint16_t* __restrict__ value, const float* __restrict__ phases,
                        const float* __restrict__ pr, const float* __restrict__ pi,
                        uint16_t* __restrict__ ret) {
  int d0 = blockIdx.x * 512 + threadIdx.x * 2;
  int c = blockIdx.y, b = blockIdx.z;
  size_t o = ((size_t)b * NCH + c) * D_DIM + d0;
  float2 r0 = *(const float2*)(pr + o);
  float2 i0 = *(const float2*)(pi + o);
  float mr0 = r0.x, mr1 = r0.y, mi0 = i0.x, mi1 = i0.y;
  size_t rowoff = ((size_t)(b * L_DIM + c * CHUNK)) * D_DIM + d0;
  const uint16_t* vp = value + rowoff;
  uint16_t* rp = ret + rowoff;
  const float* pp = phases + (size_t)(c * CHUNK) * D_DIM + d0;
  const float isd = 0.03125f;  // 1/sqrt(1024)
#pragma unroll 4
  for (int l = 0; l < CHUNK; ++l) {
    uint32_t vv = *(const uint32_t*)vp; vp += D_DIM;
    float2 ph = *(const float2*)pp; pp += D_DIM;
    float v0 = bf2f(vv & 0xffffu), v1 = bf2f(vv >> 16);
    float s0, c0, s1, c1;
    __sincosf(ph.x, &s0, &c0);
    __sincosf(ph.y, &s1, &c1);
    mr0 += v0 * c0; mi0 += v0 * s0;
    mr1 += v1 * c1; mi1 += v1 * s1;
    float o0 = (mr0 * c0 + mi0 * s0) * isd;
    float o1 = (mr1 * c1 + mi1 * s1) * isd;
    *(uint32_t*)rp = (uint32_t)f2bf(o0) | ((uint32_t)f2bf(o1) << 16);
    rp += D_DIM;
  }
}

// ---------- per-row mean / rstd over retrieved ----------
__global__ void k_stats(const uint16_t* __restrict__ ret, float* __restrict__ mu,
                        float* __restrict__ inv) {
  int m = blockIdx.x, tid = threadIdx.x;
  ushort4 v = *(const ushort4*)(ret + (size_t)m * D_DIM + tid * 4);
  float f0 = bf2f(v.x), f1 = bf2f(v.y), f2_ = bf2f(v.z), f3 = bf2f(v.w);
  float s = f0 + f1 + f2_ + f3;
  float ss = f0 * f0 + f1 * f1 + f2_ * f2_ + f3 * f3;
#pragma unroll
  for (int off = 32; off > 0; off >>= 1) {
    s += __shfl_down(s, off);
    ss += __shfl_down(ss, off);
  }
  __shared__ float a1[4], a2[4];
  int wid = tid >> 6, lane = tid & 63;
  if (lane == 0) { a1[wid] = s; a2[wid] = ss; }
  __syncthreads();
  if (tid == 0) {
    float S = a1[0] + a1[1] + a1[2] + a1[3];
    float SS = a2[0] + a2[1] + a2[2] + a2[3];
    float mm = S * (1.0f / 1024.0f);
    float var = SS * (1.0f / 1024.0f) - mm * mm;
    mu[m] = mm;
    inv[m] = rsqrtf(var + 1e-5f);
  }
}

extern "C" void kernel_launch(void* const* d_in, const int* in_sizes, int n_in,
                              void* d_out, int out_size, void* d_ws, size_t ws_size,
                              hipStream_t stream) {
  const float* x      = (const float*)d_in[0];
  const float* phases = (const float*)d_in[1];
  const float* Wv     = (const float*)d_in[2];
  const float* bv     = (const float*)d_in[3];
  const float* lng    = (const float*)d_in[4];
  const float* lnb    = (const float*)d_in[5];
  const float* Wo     = (const float*)d_in[6];
  const float* bo     = (const float*)d_in[7];
  float* out = (float*)d_out;

  char* ws = (char*)d_ws;
  uint16_t* value = (uint16_t*)(ws);                       // 32MB (value -> retrieved in-place)
  uint16_t* wv    = (uint16_t*)(ws + (32ull << 20));       // 2MB
  uint16_t* wob   = (uint16_t*)(ws + (34ull << 20));       // 2MB
  float* pr       = (float*)(ws + (36ull << 20));          // 1MB
  float* pi       = (float*)(ws + (37ull << 20));          // 1MB
  float* u        = (float*)(ws + (38ull << 20));          // 4KB
  float* vb       = (float*)(ws + (38ull << 20) + 4096);   // 4KB
  float* mu       = (float*)(ws + (39ull << 20));          // 64KB
  float* inv      = (float*)(ws + (40ull << 20));          // 64KB
  uint16_t* retr  = value;

  k_prep<<<512 + 1024, 256, 0, stream>>>(Wv, Wo, lng, lnb, bo, wv, wob, u, vb);
  k_gemm<0><<<(M_DIM / 256) * (D_DIM / 256), 512, 0, stream>>>(
      nullptr, wv, value, bv, nullptr, nullptr, nullptr, nullptr, x);
  k_passA<<<dim3(2, NCH, B_DIM), 256, 0, stream>>>(value, phases, pr, pi);
  k_passB<<<dim3(D_DIM / 256, B_DIM), 256, 0, stream>>>(pr, pi);
  k_passC<<<dim3(2, NCH, B_DIM), 256, 0, stream>>>(value, phases, pr, pi, retr);
  k_stats<<<M_DIM, 256, 0, stream>>>(retr, mu, inv);
  k_gemm<1><<<(M_DIM / 256) * (D_DIM / 256), 512, 0, stream>>>(
      retr, wob, out, u, vb, mu, inv, x, nullptr);
}

// Round 10
// 147.113 us; speedup vs baseline: 1.0991x; 1.0991x over previous
//
#include <hip/hip_runtime.h>
#include <stdint.h>

// PureOrthoPhasor: out = x + LN-epilogue GEMM( scan( GEMM(x,Wv), phases ), Wo )
// D=1024, L=4096, B=4, M = B*L = 16384.
// R10: revert to R5 (best-known: 146.4us). R7 fusion (-) and R9 f32-reg-staging
// (-) both regressed; GEMM schedule plateau confirmed across R3/R5/R6/R8
// (46-51us, 26-28% MfmaUtil). R5 = 256x256 tile, BK=64, 8 waves, merged
// 2-phase K-step with staggered lgkmcnt(8)/(4), counted vmcnt(4), T2 swizzle,
// T5 setprio, XCD swizzle, LDS-repacked bf16 epilogue, in-place passC,
// bf16 residual read in gemm2.

#define D_DIM 1024
#define L_DIM 4096
#define B_DIM 4
#define M_DIM (B_DIM * L_DIM)
#define CHUNK 64
#define NCH (L_DIM / CHUNK)
#define NT 16  // K steps (1024/64)

typedef __attribute__((ext_vector_type(8))) short short8;
typedef __attribute__((ext_vector_type(4))) float f32x4;

__device__ __forceinline__ float bf2f(uint32_t h) {
  union { uint32_t u; float f; } x; x.u = h << 16; return x.f;
}
__device__ __forceinline__ uint16_t f2bf(float f) {
  union { float f; uint32_t u; } x; x.f = f;
  uint32_t u = x.u;
  u += 0x7fffu + ((u >> 16) & 1u);   // round-to-nearest-even
  return (uint16_t)(u >> 16);
}

// ---------- merged prep: convert x, convert Wv, build Wo'/u/vb ----------
__global__ void k_prep(const float* __restrict__ x, const float* __restrict__ Wv,
                       const float* __restrict__ Wo, const float* __restrict__ g,
                       const float* __restrict__ bln, const float* __restrict__ bo,
                       uint16_t* __restrict__ xb, uint16_t* __restrict__ wv,
                       uint16_t* __restrict__ wob, float* __restrict__ u,
                       float* __restrict__ vb) {
  int blk = blockIdx.x;
  int tid = threadIdx.x;
  if (blk < 8192 + 512) {
    const float* in = (blk < 8192) ? x : Wv;
    uint16_t* outp = (blk < 8192) ? xb : wv;
    int base = (blk < 8192) ? blk : (blk - 8192);
    int i = (base * 256 + tid) * 8;
    float4 a = *(const float4*)(in + i);
    float4 b = *(const float4*)(in + i + 4);
    ushort4 o0 = { f2bf(a.x), f2bf(a.y), f2bf(a.z), f2bf(a.w) };
    ushort4 o1 = { f2bf(b.x), f2bf(b.y), f2bf(b.z), f2bf(b.w) };
    *(ushort4*)(outp + i) = o0;
    *(ushort4*)(outp + i + 4) = o1;
    return;
  }
  int e = blk - 8704;
  int d = tid * 4;
  float4 w  = *(const float4*)(Wo + (size_t)e * D_DIM + d);
  float4 gg = *(const float4*)(g + d);
  float4 bb = *(const float4*)(bln + d);
  float gw0 = gg.x * w.x, gw1 = gg.y * w.y, gw2 = gg.z * w.z, gw3 = gg.w * w.w;
  ushort4 o = { f2bf(gw0), f2bf(gw1), f2bf(gw2), f2bf(gw3) };
  *(ushort4*)(wob + (size_t)e * D_DIM + d) = o;
  float su = gw0 + gw1 + gw2 + gw3;
  float sv = bb.x * w.x + bb.y * w.y + bb.z * w.z + bb.w * w.w;
#pragma unroll
  for (int off = 32; off > 0; off >>= 1) {
    su += __shfl_down(su, off);
    sv += __shfl_down(sv, off);
  }
  __shared__ float s1[4], s2[4];
  int wid = tid >> 6, lane = tid & 63;
  if (lane == 0) { s1[wid] = su; s2[wid] = sv; }
  __syncthreads();
  if (tid == 0) {
    u[e]  = s1[0] + s1[1] + s1[2] + s1[3];
    vb[e] = s2[0] + s2[1] + s2[2] + s2[3] + bo[e];
  }
}

// ---------- 256x256 phase-interleaved bf16 MFMA GEMM (R5 schedule) ----------
// C[m][n] = sum_k A[m][k] * W[n][k].  8 waves = 2(M) x 4(N); wave owns 128x64.
// MODE 0: out(bf16) = C + p0[n]                       (coalesced via LDS repack)
// MODE 1: out(f32)  = inv[m]*C - inv[m]*mu[m]*p0[n] + p1[n] + bf2f(xres[m][n])
template <int MODE>
__global__ __launch_bounds__(512, 2) void k_gemm(
    const uint16_t* __restrict__ A, const uint16_t* __restrict__ W,
    void* __restrict__ outp,
    const float* __restrict__ p0, const float* __restrict__ p1,
    const float* __restrict__ mu, const float* __restrict__ inv,
    const uint16_t* __restrict__ xres) {
  __shared__ char lds[8 * 16384];   // 8 half-tile slots: [par*4 + {0,1:A, 2,3:B}]
  const int tid = threadIdx.x;
  const int lane = tid & 63;
  const int wid = tid >> 6;           // 0..7
  const int wm = wid >> 2;            // 0..1
  const int wn = wid & 3;             // 0..3

  // XCD swizzle: 256 blocks, 8 XCDs, 32 blocks/XCD; bn fastest within chunk.
  const int idx = blockIdx.x;
  const int bm = (idx & 7) * 8 + ((idx >> 3) >> 2);  // 0..63
  const int bn = (idx >> 3) & 3;                     // 0..3

  // staging geometry: 512 threads x 16B = 8KB round; half-tile = 128 rows x 128B.
  const int srow = tid >> 3;               // 0..63 (row within round)
  const int scb  = (tid & 7) * 16;         // 0..112
  const int scbs = scb ^ ((srow & 7) << 4);  // inverse-swizzled source col-byte

#define GLL(SRC, DST)                                                            \
  __builtin_amdgcn_global_load_lds((const __attribute__((address_space(1))) void*)(SRC), \
                                   (__attribute__((address_space(3))) void*)(DST), 16, 0, 0)

#define STAGE_A(KS, HA)                                                          \
  do {                                                                           \
    char* _d = lds + ((((KS)&1) * 4 + (HA)) << 14) + tid * 16;                   \
    const char* _s = (const char*)A +                                            \
        (size_t)(bm * 256 + (HA) * 128 + srow) * 2048 + (KS) * 128 + scbs;       \
    GLL(_s, _d);                                                                 \
    GLL(_s + (size_t)64 * 2048, _d + 8192);                                      \
  } while (0)

#define STAGE_B(KS, HB)                                                          \
  do {                                                                           \
    char* _d = lds + ((((KS)&1) * 4 + 2 + (HB)) << 14) + tid * 16;               \
    const char* _s = (const char*)W +                                            \
        (size_t)(bn * 256 + (HB) * 128 + srow) * 2048 + (KS) * 128 + scbs;       \
    GLL(_s, _d);                                                                 \
    GLL(_s + (size_t)64 * 2048, _d + 8192);                                      \
  } while (0)

  // swizzled ds_read fragment loads
  const int axor = (lane & 7) << 4;
  const int afr  = lane & 15;          // row within 16-row frag
  const int acol = (lane >> 4) * 16;   // 16B sub-col

#define LD_A(PAR, I, KK)                                                         \
  (*(const short8*)(lds + (((PAR) * 4 + wm) << 14) + ((I) * 16 + afr) * 128 +    \
                    (((KK) * 64 + acol) ^ axor)))
#define LD_B(PAR, J, KK)                                                         \
  (*(const short8*)(lds + (((PAR) * 4 + 2 + (wn >> 1)) << 14) +                  \
                    ((wn & 1) * 64 + (J) * 16 + afr) * 128 +                     \
                    (((KK) * 64 + acol) ^ axor)))

#define MFMA(AV, BV, CV) __builtin_amdgcn_mfma_f32_16x16x32_bf16(AV, BV, CV, 0, 0, 0)

  f32x4 acc[8][4];
#pragma unroll
  for (int i = 0; i < 8; ++i)
#pragma unroll
    for (int j = 0; j < 4; ++j)
      acc[i][j] = (f32x4){0.f, 0.f, 0.f, 0.f};

  // prologue: A(0) [4 loads], B(0) [4], A(1) [4]; force first 8, keep A(1).
  STAGE_A(0, 0); STAGE_A(0, 1);
  STAGE_B(0, 0); STAGE_B(0, 1);
  STAGE_A(1, 0); STAGE_A(1, 1);
  asm volatile("s_waitcnt vmcnt(4)" ::: "memory");
  __builtin_amdgcn_s_barrier();

  for (int ks = 0; ks < NT; ++ks) {
    const int par = ks & 1;
    short8 A00, A01, A02, A03, A10, A11, A12, A13;
    short8 B00, B01, B02, B03, B10, B11, B12, B13;

    // ======== phase A: 16 ds_reads (2 pinned groups of 8), stage B(ks+1),
    //          barrier, lgkmcnt(8) -> 16 MFMA kk0, lgkmcnt(0) -> 16 MFMA kk1.
    B00 = LD_B(par, 0, 0); B01 = LD_B(par, 1, 0); B02 = LD_B(par, 2, 0); B03 = LD_B(par, 3, 0);
    A00 = LD_A(par, 0, 0); A01 = LD_A(par, 1, 0); A02 = LD_A(par, 2, 0); A03 = LD_A(par, 3, 0);
    __builtin_amdgcn_sched_barrier(0);
    B10 = LD_B(par, 0, 1); B11 = LD_B(par, 1, 1); B12 = LD_B(par, 2, 1); B13 = LD_B(par, 3, 1);
    A10 = LD_A(par, 0, 1); A11 = LD_A(par, 1, 1); A12 = LD_A(par, 2, 1); A13 = LD_A(par, 3, 1);
    __builtin_amdgcn_sched_barrier(0);
    if (ks + 1 < NT) { STAGE_B(ks + 1, 0); STAGE_B(ks + 1, 1); }
    __builtin_amdgcn_s_barrier();
    asm volatile("s_waitcnt lgkmcnt(8)" ::: "memory");   // group 1 landed
    __builtin_amdgcn_sched_barrier(0);
    __builtin_amdgcn_s_setprio(1);
#pragma unroll
    for (int j = 0; j < 4; ++j) {
      const short8 bj = (j == 0) ? B00 : (j == 1) ? B01 : (j == 2) ? B02 : B03;
      acc[0][j] = MFMA(A00, bj, acc[0][j]);
      acc[1][j] = MFMA(A01, bj, acc[1][j]);
      acc[2][j] = MFMA(A02, bj, acc[2][j]);
      acc[3][j] = MFMA(A03, bj, acc[3][j]);
    }
    asm volatile("s_waitcnt lgkmcnt(0)" ::: "memory");   // group 2 landed
    __builtin_amdgcn_sched_barrier(0);
#pragma unroll
    for (int j = 0; j < 4; ++j) {
      const short8 bj = (j == 0) ? B10 : (j == 1) ? B11 : (j == 2) ? B12 : B13;
      acc[0][j] = MFMA(A10, bj, acc[0][j]);
      acc[1][j] = MFMA(A11, bj, acc[1][j]);
      acc[2][j] = MFMA(A12, bj, acc[2][j]);
      acc[3][j] = MFMA(A13, bj, acc[3][j]);
    }
    __builtin_amdgcn_s_setprio(0);
    __builtin_amdgcn_s_barrier();

    // ======== phase B: 8 ds_reads (2 pinned groups of 4), lgkmcnt(4) ->
    //          16 MFMA kk0, lgkmcnt(0)+barrier -> stage A(ks+2), 16 MFMA kk1.
    A00 = LD_A(par, 4, 0); A01 = LD_A(par, 5, 0); A02 = LD_A(par, 6, 0); A03 = LD_A(par, 7, 0);
    __builtin_amdgcn_sched_barrier(0);
    A10 = LD_A(par, 4, 1); A11 = LD_A(par, 5, 1); A12 = LD_A(par, 6, 1); A13 = LD_A(par, 7, 1);
    __builtin_amdgcn_sched_barrier(0);
    asm volatile("s_waitcnt lgkmcnt(4)" ::: "memory");   // kk0 group landed
    __builtin_amdgcn_sched_barrier(0);
    __builtin_amdgcn_s_setprio(1);
#pragma unroll
    for (int j = 0; j < 4; ++j) {
      const short8 bj = (j == 0) ? B00 : (j == 1) ? B01 : (j == 2) ? B02 : B03;
      acc[4][j] = MFMA(A00, bj, acc[4][j]);
      acc[5][j] = MFMA(A01, bj, acc[5][j]);
      acc[6][j] = MFMA(A02, bj, acc[6][j]);
      acc[7][j] = MFMA(A03, bj, acc[7][j]);
    }
    __builtin_amdgcn_s_setprio(0);
    asm volatile("s_waitcnt lgkmcnt(0)" ::: "memory");   // all par-A reads done (this wave)
    __builtin_amdgcn_sched_barrier(0);
    __builtin_amdgcn_s_barrier();                        // ... across all waves
    __builtin_amdgcn_sched_barrier(0);
    if (ks + 2 < NT) { STAGE_A(ks + 2, 0); STAGE_A(ks + 2, 1); }
    __builtin_amdgcn_s_setprio(1);
#pragma unroll
    for (int j = 0; j < 4; ++j) {
      const short8 bj = (j == 0) ? B10 : (j == 1) ? B11 : (j == 2) ? B12 : B13;
      acc[4][j] = MFMA(A10, bj, acc[4][j]);
      acc[5][j] = MFMA(A11, bj, acc[5][j]);
      acc[6][j] = MFMA(A12, bj, acc[6][j]);
      acc[7][j] = MFMA(A13, bj, acc[7][j]);
    }
    __builtin_amdgcn_s_setprio(0);
    // boundary: force {A(ks+1),B(ks+1)}, leave A(ks+2) in flight
    if (ks == NT - 2) { asm volatile("s_waitcnt vmcnt(0)" ::: "memory"); }
    else              { asm volatile("s_waitcnt vmcnt(4)" ::: "memory"); }
    __builtin_amdgcn_s_barrier();
  }

  // D layout per frag: col = lane&15, row = (lane>>4)*4 + reg
  if (MODE == 0) {
    // Repack through LDS -> fully-coalesced 16B bf16 stores.
    uint16_t* outv = (uint16_t*)outp;
    __syncthreads();
#pragma unroll
    for (int i = 0; i < 8; ++i)
#pragma unroll
      for (int r = 0; r < 4; ++r) {
        int row = wm * 128 + i * 16 + (lane >> 4) * 4 + r;
#pragma unroll
        for (int j = 0; j < 4; ++j) {
          int ncol = wn * 64 + j * 16 + (lane & 15);
          float v = acc[i][j][r] + p0[bn * 256 + ncol];
          *(uint16_t*)(lds + row * 512 + ((ncol * 2) ^ ((row & 7) << 4))) = f2bf(v);
        }
      }
    __syncthreads();
    {
      int row = tid >> 1, half = tid & 1;
      uint16_t* gdst = outv + (size_t)(bm * 256 + row) * D_DIM + bn * 256 + half * 128;
#pragma unroll
      for (int s = 0; s < 16; ++s) {
        short8 v = *(const short8*)(lds + row * 512 +
                                    ((half * 256 + s * 16) ^ ((row & 7) << 4)));
        *(short8*)(gdst + s * 8) = v;
      }
    }
  } else {
    float* outf = (float*)outp;
#pragma unroll
    for (int i = 0; i < 8; ++i)
#pragma unroll
      for (int r = 0; r < 4; ++r) {
        int m = bm * 256 + wm * 128 + i * 16 + (lane >> 4) * 4 + r;
        float im = inv[m], mm = mu[m];
#pragma unroll
        for (int j = 0; j < 4; ++j) {
          int n = bn * 256 + wn * 64 + j * 16 + (lane & 15);
          outf[(size_t)m * D_DIM + n] =
              im * acc[i][j][r] - im * mm * p0[n] + p1[n] +
              bf2f(xres[(size_t)m * D_DIM + n]);
        }
      }
  }
#undef GLL
#undef STAGE_A
#undef STAGE_B
#undef LD_A
#undef LD_B
#undef MFMA
}

// ---------- pass A: per-chunk partial sums of value*cos / value*sin ----------
__global__ void k_passA(const uint16_t* __restrict__ value, const float* __restrict__ phases,
                        float* __restrict__ pr, float* __restrict__ pi) {
  int d0 = blockIdx.x * 512 + threadIdx.x * 2;
  int c = blockIdx.y, b = blockIdx.z;
  const uint16_t* vp = value + ((size_t)(b * L_DIM + c * CHUNK)) * D_DIM + d0;
  const float* pp = phases + (size_t)(c * CHUNK) * D_DIM + d0;
  float sr0 = 0, si0 = 0, sr1 = 0, si1 = 0;
#pragma unroll 4
  for (int l = 0; l < CHUNK; ++l) {
    uint32_t vv = *(const uint32_t*)vp; vp += D_DIM;
    float2 ph = *(const float2*)pp; pp += D_DIM;
    float v0 = bf2f(vv & 0xffffu), v1 = bf2f(vv >> 16);
    float s0, c0, s1, c1;
    __sincosf(ph.x, &s0, &c0);
    __sincosf(ph.y, &s1, &c1);
    sr0 += v0 * c0; si0 += v0 * s0;
    sr1 += v1 * c1; si1 += v1 * s1;
  }
  size_t o = ((size_t)b * NCH + c) * D_DIM + d0;
  *(float2*)(pr + o) = make_float2(sr0, sr1);
  *(float2*)(pi + o) = make_float2(si0, si1);
}

// ---------- pass B: in-place exclusive scan of the NCH chunk partials ----------
__global__ void k_passB(float* __restrict__ pr, float* __restrict__ pi) {
  int d = blockIdx.x * 256 + threadIdx.x;
  int b = blockIdx.y;
  size_t base = (size_t)b * NCH * D_DIM + d;
  float r[NCH], im[NCH];
#pragma unroll
  for (int c = 0; c < NCH; ++c) r[c] = pr[base + (size_t)c * D_DIM];
#pragma unroll
  for (int c = 0; c < NCH; ++c) im[c] = pi[base + (size_t)c * D_DIM];
  float rr = 0, ri = 0;
#pragma unroll
  for (int c = 0; c < NCH; ++c) {
    float t = r[c]; r[c] = rr; rr += t;
    t = im[c]; im[c] = ri; ri += t;
  }
#pragma unroll
  for (int c = 0; c < NCH; ++c) pr[base + (size_t)c * D_DIM] = r[c];
#pragma unroll
  for (int c = 0; c < NCH; ++c) pi[base + (size_t)c * D_DIM] = im[c];
}

// ---------- pass C: replay chunk with offset, write retrieved (bf16, IN-PLACE) ----------
__global__ void k_passC(const uint16_t* __restrict__ value, const float* __restrict__ phases,
                        const float* __restrict__ pr, const float* __restrict__ pi,
                        uint16_t* __restrict__ ret) {
  int d0 = blockIdx.x * 512 + threadIdx.x * 2;
  int c = blockIdx.y, b = blockIdx.z;
  size_t o = ((size_t)b * NCH + c) * D_DIM + d0;
  float2 r0 = *(const float2*)(pr + o);
  float2 i0 = *(const float2*)(pi + o);
  float mr0 = r0.x, mr1 = r0.y, mi0 = i0.x, mi1 = i0.y;
  size_t rowoff = ((size_t)(b * L_DIM + c * CHUNK)) * D_DIM + d0;
  const uint16_t* vp = value + rowoff;
  uint16_t* rp = ret + rowoff;
  const float* pp = phases + (size_t)(c * CHUNK) * D_DIM + d0;
  const float isd = 0.03125f;  // 1/sqrt(1024)
#pragma unroll 4
  for (int l = 0; l < CHUNK; ++l) {
    uint32_t vv = *(const uint32_t*)vp; vp += D_DIM;
    float2 ph = *(const float2*)pp; pp += D_DIM;
    float v0 = bf2f(vv & 0xffffu), v1 = bf2f(vv >> 16);
    float s0, c0, s1, c1;
    __sincosf(ph.x, &s0, &c0);
    __sincosf(ph.y, &s1, &c1);
    mr0 += v0 * c0; mi0 += v0 * s0;
    mr1 += v1 * c1; mi1 += v1 * s1;
    float o0 = (mr0 * c0 + mi0 * s0) * isd;
    float o1 = (mr1 * c1 + mi1 * s1) * isd;
    *(uint32_t*)rp = (uint32_t)f2bf(o0) | ((uint32_t)f2bf(o1) << 16);
    rp += D_DIM;
  }
}

// ---------- per-row mean / rstd over retrieved ----------
__global__ void k_stats(const uint16_t* __restrict__ ret, float* __restrict__ mu,
                        float* __restrict__ inv) {
  int m = blockIdx.x, tid = threadIdx.x;
  ushort4 v = *(const ushort4*)(ret + (size_t)m * D_DIM + tid * 4);
  float f0 = bf2f(v.x), f1 = bf2f(v.y), f2_ = bf2f(v.z), f3 = bf2f(v.w);
  float s = f0 + f1 + f2_ + f3;
  float ss = f0 * f0 + f1 * f1 + f2_ * f2_ + f3 * f3;
#pragma unroll
  for (int off = 32; off > 0; off >>= 1) {
    s += __shfl_down(s, off);
    ss += __shfl_down(ss, off);
  }
  __shared__ float a1[4], a2[4];
  int wid = tid >> 6, lane = tid & 63;
  if (lane == 0) { a1[wid] = s; a2[wid] = ss; }
  __syncthreads();
  if (tid == 0) {
    float S = a1[0] + a1[1] + a1[2] + a1[3];
    float SS = a2[0] + a2[1] + a2[2] + a2[3];
    float mm = S * (1.0f / 1024.0f);
    float var = SS * (1.0f / 1024.0f) - mm * mm;
    mu[m] = mm;
    inv[m] = rsqrtf(var + 1e-5f);
  }
}

extern "C" void kernel_launch(void* const* d_in, const int* in_sizes, int n_in,
                              void* d_out, int out_size, void* d_ws, size_t ws_size,
                              hipStream_t stream) {
  const float* x      = (const float*)d_in[0];
  const float* phases = (const float*)d_in[1];
  const float* Wv     = (const float*)d_in[2];
  const float* bv     = (const float*)d_in[3];
  const float* lng    = (const float*)d_in[4];
  const float* lnb    = (const float*)d_in[5];
  const float* Wo     = (const float*)d_in[6];
  const float* bo     = (const float*)d_in[7];
  float* out = (float*)d_out;

  char* ws = (char*)d_ws;
  uint16_t* xb    = (uint16_t*)(ws);                       // 32MB (bf16 x; GEMM1 A + GEMM2 residual)
  uint16_t* value = (uint16_t*)(ws + (32ull << 20));       // 32MB (value -> retrieved in-place)
  uint16_t* wv    = (uint16_t*)(ws + (64ull << 20));       // 2MB
  uint16_t* wob   = (uint16_t*)(ws + (66ull << 20));       // 2MB
  float* pr       = (float*)(ws + (68ull << 20));          // 1MB
  float* pi       = (float*)(ws + (69ull << 20));          // 1MB
  float* u        = (float*)(ws + (70ull << 20));          // 4KB
  float* vb       = (float*)(ws + (70ull << 20) + 4096);   // 4KB
  float* mu       = (float*)(ws + (71ull << 20));          // 64KB
  float* inv      = (float*)(ws + (72ull << 20));          // 64KB
  uint16_t* retr  = value;

  k_prep<<<8192 + 512 + 1024, 256, 0, stream>>>(x, Wv, Wo, lng, lnb, bo,
                                                xb, wv, wob, u, vb);
  k_gemm<0><<<(M_DIM / 256) * (D_DIM / 256), 512, 0, stream>>>(
      xb, wv, value, bv, nullptr, nullptr, nullptr, nullptr);
  k_passA<<<dim3(2, NCH, B_DIM), 256, 0, stream>>>(value, phases, pr, pi);
  k_passB<<<dim3(D_DIM / 256, B_DIM), 256, 0, stream>>>(pr, pi);
  k_passC<<<dim3(2, NCH, B_DIM), 256, 0, stream>>>(value, phases, pr, pi, retr);
  k_stats<<<M_DIM, 256, 0, stream>>>(retr, mu, inv);
  k_gemm<1><<<(M_DIM / 256) * (D_DIM / 256), 512, 0, stream>>>(
      retr, wob, out, u, vb, mu, inv, xb);
}

// Round 11
// 143.662 us; speedup vs baseline: 1.1255x; 1.0240x over previous
//
#include <hip/hip_runtime.h>
#include <stdint.h>

// PureOrthoPhasor: out = x + LN-epilogue GEMM( scan( GEMM(x,Wv), phases ), Wo )
// D=1024, L=4096, B=4, M = B*L = 16384.
// R11: R10 base (best-known, 147.1us) + two risk-free micro-opts:
//  - k_stats: wave-per-row, 32B/lane contiguous short8 loads, shfl-only
//    reduce (was 8B/lane + LDS round-trip, 4.6 TB/s).
//  - passA: 4 cols/thread (uint2 value + float4 phases). Per-column summation
//    order unchanged -> bit-identical pr/pi.
// GEMM untouched: R5/R10 schedule (4-way-verified plateau 46-51us @27% MfmaUtil).

#define D_DIM 1024
#define L_DIM 4096
#define B_DIM 4
#define M_DIM (B_DIM * L_DIM)
#define CHUNK 64
#define NCH (L_DIM / CHUNK)
#define NT 16  // K steps (1024/64)

typedef __attribute__((ext_vector_type(8))) short short8;
typedef __attribute__((ext_vector_type(4))) float f32x4;

__device__ __forceinline__ float bf2f(uint32_t h) {
  union { uint32_t u; float f; } x; x.u = h << 16; return x.f;
}
__device__ __forceinline__ uint16_t f2bf(float f) {
  union { float f; uint32_t u; } x; x.f = f;
  uint32_t u = x.u;
  u += 0x7fffu + ((u >> 16) & 1u);   // round-to-nearest-even
  return (uint16_t)(u >> 16);
}

// ---------- merged prep: convert x, convert Wv, build Wo'/u/vb ----------
__global__ void k_prep(const float* __restrict__ x, const float* __restrict__ Wv,
                       const float* __restrict__ Wo, const float* __restrict__ g,
                       const float* __restrict__ bln, const float* __restrict__ bo,
                       uint16_t* __restrict__ xb, uint16_t* __restrict__ wv,
                       uint16_t* __restrict__ wob, float* __restrict__ u,
                       float* __restrict__ vb) {
  int blk = blockIdx.x;
  int tid = threadIdx.x;
  if (blk < 8192 + 512) {
    const float* in = (blk < 8192) ? x : Wv;
    uint16_t* outp = (blk < 8192) ? xb : wv;
    int base = (blk < 8192) ? blk : (blk - 8192);
    int i = (base * 256 + tid) * 8;
    float4 a = *(const float4*)(in + i);
    float4 b = *(const float4*)(in + i + 4);
    ushort4 o0 = { f2bf(a.x), f2bf(a.y), f2bf(a.z), f2bf(a.w) };
    ushort4 o1 = { f2bf(b.x), f2bf(b.y), f2bf(b.z), f2bf(b.w) };
    *(ushort4*)(outp + i) = o0;
    *(ushort4*)(outp + i + 4) = o1;
    return;
  }
  int e = blk - 8704;
  int d = tid * 4;
  float4 w  = *(const float4*)(Wo + (size_t)e * D_DIM + d);
  float4 gg = *(const float4*)(g + d);
  float4 bb = *(const float4*)(bln + d);
  float gw0 = gg.x * w.x, gw1 = gg.y * w.y, gw2 = gg.z * w.z, gw3 = gg.w * w.w;
  ushort4 o = { f2bf(gw0), f2bf(gw1), f2bf(gw2), f2bf(gw3) };
  *(ushort4*)(wob + (size_t)e * D_DIM + d) = o;
  float su = gw0 + gw1 + gw2 + gw3;
  float sv = bb.x * w.x + bb.y * w.y + bb.z * w.z + bb.w * w.w;
#pragma unroll
  for (int off = 32; off > 0; off >>= 1) {
    su += __shfl_down(su, off);
    sv += __shfl_down(sv, off);
  }
  __shared__ float s1[4], s2[4];
  int wid = tid >> 6, lane = tid & 63;
  if (lane == 0) { s1[wid] = su; s2[wid] = sv; }
  __syncthreads();
  if (tid == 0) {
    u[e]  = s1[0] + s1[1] + s1[2] + s1[3];
    vb[e] = s2[0] + s2[1] + s2[2] + s2[3] + bo[e];
  }
}

// ---------- 256x256 phase-interleaved bf16 MFMA GEMM (R5 schedule) ----------
// C[m][n] = sum_k A[m][k] * W[n][k].  8 waves = 2(M) x 4(N); wave owns 128x64.
// MODE 0: out(bf16) = C + p0[n]                       (coalesced via LDS repack)
// MODE 1: out(f32)  = inv[m]*C - inv[m]*mu[m]*p0[n] + p1[n] + bf2f(xres[m][n])
template <int MODE>
__global__ __launch_bounds__(512, 2) void k_gemm(
    const uint16_t* __restrict__ A, const uint16_t* __restrict__ W,
    void* __restrict__ outp,
    const float* __restrict__ p0, const float* __restrict__ p1,
    const float* __restrict__ mu, const float* __restrict__ inv,
    const uint16_t* __restrict__ xres) {
  __shared__ char lds[8 * 16384];   // 8 half-tile slots: [par*4 + {0,1:A, 2,3:B}]
  const int tid = threadIdx.x;
  const int lane = tid & 63;
  const int wid = tid >> 6;           // 0..7
  const int wm = wid >> 2;            // 0..1
  const int wn = wid & 3;             // 0..3

  // XCD swizzle: 256 blocks, 8 XCDs, 32 blocks/XCD; bn fastest within chunk.
  const int idx = blockIdx.x;
  const int bm = (idx & 7) * 8 + ((idx >> 3) >> 2);  // 0..63
  const int bn = (idx >> 3) & 3;                     // 0..3

  // staging geometry: 512 threads x 16B = 8KB round; half-tile = 128 rows x 128B.
  const int srow = tid >> 3;               // 0..63 (row within round)
  const int scb  = (tid & 7) * 16;         // 0..112
  const int scbs = scb ^ ((srow & 7) << 4);  // inverse-swizzled source col-byte

#define GLL(SRC, DST)                                                            \
  __builtin_amdgcn_global_load_lds((const __attribute__((address_space(1))) void*)(SRC), \
                                   (__attribute__((address_space(3))) void*)(DST), 16, 0, 0)

#define STAGE_A(KS, HA)                                                          \
  do {                                                                           \
    char* _d = lds + ((((KS)&1) * 4 + (HA)) << 14) + tid * 16;                   \
    const char* _s = (const char*)A +                                            \
        (size_t)(bm * 256 + (HA) * 128 + srow) * 2048 + (KS) * 128 + scbs;       \
    GLL(_s, _d);                                                                 \
    GLL(_s + (size_t)64 * 2048, _d + 8192);                                      \
  } while (0)

#define STAGE_B(KS, HB)                                                          \
  do {                                                                           \
    char* _d = lds + ((((KS)&1) * 4 + 2 + (HB)) << 14) + tid * 16;               \
    const char* _s = (const char*)W +                                            \
        (size_t)(bn * 256 + (HB) * 128 + srow) * 2048 + (KS) * 128 + scbs;       \
    GLL(_s, _d);                                                                 \
    GLL(_s + (size_t)64 * 2048, _d + 8192);                                      \
  } while (0)

  // swizzled ds_read fragment loads
  const int axor = (lane & 7) << 4;
  const int afr  = lane & 15;          // row within 16-row frag
  const int acol = (lane >> 4) * 16;   // 16B sub-col

#define LD_A(PAR, I, KK)                                                         \
  (*(const short8*)(lds + (((PAR) * 4 + wm) << 14) + ((I) * 16 + afr) * 128 +    \
                    (((KK) * 64 + acol) ^ axor)))
#define LD_B(PAR, J, KK)                                                         \
  (*(const short8*)(lds + (((PAR) * 4 + 2 + (wn >> 1)) << 14) +                  \
                    ((wn & 1) * 64 + (J) * 16 + afr) * 128 +                     \
                    (((KK) * 64 + acol) ^ axor)))

#define MFMA(AV, BV, CV) __builtin_amdgcn_mfma_f32_16x16x32_bf16(AV, BV, CV, 0, 0, 0)

  f32x4 acc[8][4];
#pragma unroll
  for (int i = 0; i < 8; ++i)
#pragma unroll
    for (int j = 0; j < 4; ++j)
      acc[i][j] = (f32x4){0.f, 0.f, 0.f, 0.f};

  // prologue: A(0) [4 loads], B(0) [4], A(1) [4]; force first 8, keep A(1).
  STAGE_A(0, 0); STAGE_A(0, 1);
  STAGE_B(0, 0); STAGE_B(0, 1);
  STAGE_A(1, 0); STAGE_A(1, 1);
  asm volatile("s_waitcnt vmcnt(4)" ::: "memory");
  __builtin_amdgcn_s_barrier();

  for (int ks = 0; ks < NT; ++ks) {
    const int par = ks & 1;
    short8 A00, A01, A02, A03, A10, A11, A12, A13;
    short8 B00, B01, B02, B03, B10, B11, B12, B13;

    // ======== phase A: 16 ds_reads (2 pinned groups of 8), stage B(ks+1),
    //          barrier, lgkmcnt(8) -> 16 MFMA kk0, lgkmcnt(0) -> 16 MFMA kk1.
    B00 = LD_B(par, 0, 0); B01 = LD_B(par, 1, 0); B02 = LD_B(par, 2, 0); B03 = LD_B(par, 3, 0);
    A00 = LD_A(par, 0, 0); A01 = LD_A(par, 1, 0); A02 = LD_A(par, 2, 0); A03 = LD_A(par, 3, 0);
    __builtin_amdgcn_sched_barrier(0);
    B10 = LD_B(par, 0, 1); B11 = LD_B(par, 1, 1); B12 = LD_B(par, 2, 1); B13 = LD_B(par, 3, 1);
    A10 = LD_A(par, 0, 1); A11 = LD_A(par, 1, 1); A12 = LD_A(par, 2, 1); A13 = LD_A(par, 3, 1);
    __builtin_amdgcn_sched_barrier(0);
    if (ks + 1 < NT) { STAGE_B(ks + 1, 0); STAGE_B(ks + 1, 1); }
    __builtin_amdgcn_s_barrier();
    asm volatile("s_waitcnt lgkmcnt(8)" ::: "memory");   // group 1 landed
    __builtin_amdgcn_sched_barrier(0);
    __builtin_amdgcn_s_setprio(1);
#pragma unroll
    for (int j = 0; j < 4; ++j) {
      const short8 bj = (j == 0) ? B00 : (j == 1) ? B01 : (j == 2) ? B02 : B03;
      acc[0][j] = MFMA(A00, bj, acc[0][j]);
      acc[1][j] = MFMA(A01, bj, acc[1][j]);
      acc[2][j] = MFMA(A02, bj, acc[2][j]);
      acc[3][j] = MFMA(A03, bj, acc[3][j]);
    }
    asm volatile("s_waitcnt lgkmcnt(0)" ::: "memory");   // group 2 landed
    __builtin_amdgcn_sched_barrier(0);
#pragma unroll
    for (int j = 0; j < 4; ++j) {
      const short8 bj = (j == 0) ? B10 : (j == 1) ? B11 : (j == 2) ? B12 : B13;
      acc[0][j] = MFMA(A10, bj, acc[0][j]);
      acc[1][j] = MFMA(A11, bj, acc[1][j]);
      acc[2][j] = MFMA(A12, bj, acc[2][j]);
      acc[3][j] = MFMA(A13, bj, acc[3][j]);
    }
    __builtin_amdgcn_s_setprio(0);
    __builtin_amdgcn_s_barrier();

    // ======== phase B: 8 ds_reads (2 pinned groups of 4), lgkmcnt(4) ->
    //          16 MFMA kk0, lgkmcnt(0)+barrier -> stage A(ks+2), 16 MFMA kk1.
    A00 = LD_A(par, 4, 0); A01 = LD_A(par, 5, 0); A02 = LD_A(par, 6, 0); A03 = LD_A(par, 7, 0);
    __builtin_amdgcn_sched_barrier(0);
    A10 = LD_A(par, 4, 1); A11 = LD_A(par, 5, 1); A12 = LD_A(par, 6, 1); A13 = LD_A(par, 7, 1);
    __builtin_amdgcn_sched_barrier(0);
    asm volatile("s_waitcnt lgkmcnt(4)" ::: "memory");   // kk0 group landed
    __builtin_amdgcn_sched_barrier(0);
    __builtin_amdgcn_s_setprio(1);
#pragma unroll
    for (int j = 0; j < 4; ++j) {
      const short8 bj = (j == 0) ? B00 : (j == 1) ? B01 : (j == 2) ? B02 : B03;
      acc[4][j] = MFMA(A00, bj, acc[4][j]);
      acc[5][j] = MFMA(A01, bj, acc[5][j]);
      acc[6][j] = MFMA(A02, bj, acc[6][j]);
      acc[7][j] = MFMA(A03, bj, acc[7][j]);
    }
    __builtin_amdgcn_s_setprio(0);
    asm volatile("s_waitcnt lgkmcnt(0)" ::: "memory");   // all par-A reads done (this wave)
    __builtin_amdgcn_sched_barrier(0);
    __builtin_amdgcn_s_barrier();                        // ... across all waves
    __builtin_amdgcn_sched_barrier(0);
    if (ks + 2 < NT) { STAGE_A(ks + 2, 0); STAGE_A(ks + 2, 1); }
    __builtin_amdgcn_s_setprio(1);
#pragma unroll
    for (int j = 0; j < 4; ++j) {
      const short8 bj = (j == 0) ? B10 : (j == 1) ? B11 : (j == 2) ? B12 : B13;
      acc[4][j] = MFMA(A10, bj, acc[4][j]);
      acc[5][j] = MFMA(A11, bj, acc[5][j]);
      acc[6][j] = MFMA(A12, bj, acc[6][j]);
      acc[7][j] = MFMA(A13, bj, acc[7][j]);
    }
    __builtin_amdgcn_s_setprio(0);
    // boundary: force {A(ks+1),B(ks+1)}, leave A(ks+2) in flight
    if (ks == NT - 2) { asm volatile("s_waitcnt vmcnt(0)" ::: "memory"); }
    else              { asm volatile("s_waitcnt vmcnt(4)" ::: "memory"); }
    __builtin_amdgcn_s_barrier();
  }

  // D layout per frag: col = lane&15, row = (lane>>4)*4 + reg
  if (MODE == 0) {
    // Repack through LDS -> fully-coalesced 16B bf16 stores.
    uint16_t* outv = (uint16_t*)outp;
    __syncthreads();
#pragma unroll
    for (int i = 0; i < 8; ++i)
#pragma unroll
      for (int r = 0; r < 4; ++r) {
        int row = wm * 128 + i * 16 + (lane >> 4) * 4 + r;
#pragma unroll
        for (int j = 0; j < 4; ++j) {
          int ncol = wn * 64 + j * 16 + (lane & 15);
          float v = acc[i][j][r] + p0[bn * 256 + ncol];
          *(uint16_t*)(lds + row * 512 + ((ncol * 2) ^ ((row & 7) << 4))) = f2bf(v);
        }
      }
    __syncthreads();
    {
      int row = tid >> 1, half = tid & 1;
      uint16_t* gdst = outv + (size_t)(bm * 256 + row) * D_DIM + bn * 256 + half * 128;
#pragma unroll
      for (int s = 0; s < 16; ++s) {
        short8 v = *(const short8*)(lds + row * 512 +
                                    ((half * 256 + s * 16) ^ ((row & 7) << 4)));
        *(short8*)(gdst + s * 8) = v;
      }
    }
  } else {
    float* outf = (float*)outp;
#pragma unroll
    for (int i = 0; i < 8; ++i)
#pragma unroll
      for (int r = 0; r < 4; ++r) {
        int m = bm * 256 + wm * 128 + i * 16 + (lane >> 4) * 4 + r;
        float im = inv[m], mm = mu[m];
#pragma unroll
        for (int j = 0; j < 4; ++j) {
          int n = bn * 256 + wn * 64 + j * 16 + (lane & 15);
          outf[(size_t)m * D_DIM + n] =
              im * acc[i][j][r] - im * mm * p0[n] + p1[n] +
              bf2f(xres[(size_t)m * D_DIM + n]);
        }
      }
  }
#undef GLL
#undef STAGE_A
#undef STAGE_B
#undef LD_A
#undef LD_B
#undef MFMA
}

// ---------- pass A: per-chunk partial sums of value*cos / value*sin ----------
// 4 cols/thread (uint2 value + float4 phases); per-column row order unchanged.
__global__ void k_passA(const uint16_t* __restrict__ value, const float* __restrict__ phases,
                        float* __restrict__ pr, float* __restrict__ pi) {
  int d0 = threadIdx.x * 4;
  int c = blockIdx.y, b = blockIdx.z;
  const uint16_t* vp = value + ((size_t)(b * L_DIM + c * CHUNK)) * D_DIM + d0;
  const float* pp = phases + (size_t)(c * CHUNK) * D_DIM + d0;
  float sr0 = 0, si0 = 0, sr1 = 0, si1 = 0, sr2 = 0, si2 = 0, sr3 = 0, si3 = 0;
#pragma unroll 4
  for (int l = 0; l < CHUNK; ++l) {
    uint2 vv = *(const uint2*)vp; vp += D_DIM;
    float4 ph = *(const float4*)pp; pp += D_DIM;
    float v0 = bf2f(vv.x & 0xffffu), v1 = bf2f(vv.x >> 16);
    float v2 = bf2f(vv.y & 0xffffu), v3 = bf2f(vv.y >> 16);
    float s0, c0, s1, c1, s2, c2, s3, c3;
    __sincosf(ph.x, &s0, &c0);
    __sincosf(ph.y, &s1, &c1);
    __sincosf(ph.z, &s2, &c2);
    __sincosf(ph.w, &s3, &c3);
    sr0 += v0 * c0; si0 += v0 * s0;
    sr1 += v1 * c1; si1 += v1 * s1;
    sr2 += v2 * c2; si2 += v2 * s2;
    sr3 += v3 * c3; si3 += v3 * s3;
  }
  size_t o = ((size_t)b * NCH + c) * D_DIM + d0;
  *(float4*)(pr + o) = make_float4(sr0, sr1, sr2, sr3);
  *(float4*)(pi + o) = make_float4(si0, si1, si2, si3);
}

// ---------- pass B: in-place exclusive scan of the NCH chunk partials ----------
__global__ void k_passB(float* __restrict__ pr, float* __restrict__ pi) {
  int d = blockIdx.x * 256 + threadIdx.x;
  int b = blockIdx.y;
  size_t base = (size_t)b * NCH * D_DIM + d;
  float r[NCH], im[NCH];
#pragma unroll
  for (int c = 0; c < NCH; ++c) r[c] = pr[base + (size_t)c * D_DIM];
#pragma unroll
  for (int c = 0; c < NCH; ++c) im[c] = pi[base + (size_t)c * D_DIM];
  float rr = 0, ri = 0;
#pragma unroll
  for (int c = 0; c < NCH; ++c) {
    float t = r[c]; r[c] = rr; rr += t;
    t = im[c]; im[c] = ri; ri += t;
  }
#pragma unroll
  for (int c = 0; c < NCH; ++c) pr[base + (size_t)c * D_DIM] = r[c];
#pragma unroll
  for (int c = 0; c < NCH; ++c) pi[base + (size_t)c * D_DIM] = im[c];
}

// ---------- pass C: replay chunk with offset, write retrieved (bf16, IN-PLACE) ----------
__global__ void k_passC(const uint16_t* __restrict__ value, const float* __restrict__ phases,
                        const float* __restrict__ pr, const float* __restrict__ pi,
                        uint16_t* __restrict__ ret) {
  int d0 = blockIdx.x * 512 + threadIdx.x * 2;
  int c = blockIdx.y, b = blockIdx.z;
  size_t o = ((size_t)b * NCH + c) * D_DIM + d0;
  float2 r0 = *(const float2*)(pr + o);
  float2 i0 = *(const float2*)(pi + o);
  float mr0 = r0.x, mr1 = r0.y, mi0 = i0.x, mi1 = i0.y;
  size_t rowoff = ((size_t)(b * L_DIM + c * CHUNK)) * D_DIM + d0;
  const uint16_t* vp = value + rowoff;
  uint16_t* rp = ret + rowoff;
  const float* pp = phases + (size_t)(c * CHUNK) * D_DIM + d0;
  const float isd = 0.03125f;  // 1/sqrt(1024)
#pragma unroll 4
  for (int l = 0; l < CHUNK; ++l) {
    uint32_t vv = *(const uint32_t*)vp; vp += D_DIM;
    float2 ph = *(const float2*)pp; pp += D_DIM;
    float v0 = bf2f(vv & 0xffffu), v1 = bf2f(vv >> 16);
    float s0, c0, s1, c1;
    __sincosf(ph.x, &s0, &c0);
    __sincosf(ph.y, &s1, &c1);
    mr0 += v0 * c0; mi0 += v0 * s0;
    mr1 += v1 * c1; mi1 += v1 * s1;
    float o0 = (mr0 * c0 + mi0 * s0) * isd;
    float o1 = (mr1 * c1 + mi1 * s1) * isd;
    *(uint32_t*)rp = (uint32_t)f2bf(o0) | ((uint32_t)f2bf(o1) << 16);
    rp += D_DIM;
  }
}

// ---------- per-row mean / rstd: one wave per row, 32B/lane contiguous ----------
__global__ void k_stats(const uint16_t* __restrict__ ret, float* __restrict__ mu,
                        float* __restrict__ inv) {
  int tid = threadIdx.x;
  int wid = tid >> 6, lane = tid & 63;
  int m = blockIdx.x * 4 + wid;
  const uint16_t* p = ret + (size_t)m * D_DIM + lane * 16;
  short8 a = *(const short8*)p;
  short8 b = *(const short8*)(p + 8);
  float s = 0.f, ss = 0.f;
#pragma unroll
  for (int j = 0; j < 8; ++j) {
    float f = bf2f((uint16_t)a[j]);
    s += f; ss += f * f;
  }
#pragma unroll
  for (int j = 0; j < 8; ++j) {
    float f = bf2f((uint16_t)b[j]);
    s += f; ss += f * f;
  }
#pragma unroll
  for (int off = 32; off > 0; off >>= 1) {
    s += __shfl_down(s, off);
    ss += __shfl_down(ss, off);
  }
  if (lane == 0) {
    float mm = s * (1.0f / 1024.0f);
    float var = ss * (1.0f / 1024.0f) - mm * mm;
    mu[m] = mm;
    inv[m] = rsqrtf(var + 1e-5f);
  }
}

extern "C" void kernel_launch(void* const* d_in, const int* in_sizes, int n_in,
                              void* d_out, int out_size, void* d_ws, size_t ws_size,
                              hipStream_t stream) {
  const float* x      = (const float*)d_in[0];
  const float* phases = (const float*)d_in[1];
  const float* Wv     = (const float*)d_in[2];
  const float* bv     = (const float*)d_in[3];
  const float* lng    = (const float*)d_in[4];
  const float* lnb    = (const float*)d_in[5];
  const float* Wo     = (const float*)d_in[6];
  const float* bo     = (const float*)d_in[7];
  float* out = (float*)d_out;

  char* ws = (char*)d_ws;
  uint16_t* xb    = (uint16_t*)(ws);                       // 32MB (bf16 x; GEMM1 A + GEMM2 residual)
  uint16_t* value = (uint16_t*)(ws + (32ull << 20));       // 32MB (value -> retrieved in-place)
  uint16_t* wv    = (uint16_t*)(ws + (64ull << 20));       // 2MB
  uint16_t* wob   = (uint16_t*)(ws + (66ull << 20));       // 2MB
  float* pr       = (float*)(ws + (68ull << 20));          // 1MB
  float* pi       = (float*)(ws + (69ull << 20));          // 1MB
  float* u        = (float*)(ws + (70ull << 20));          // 4KB
  float* vb       = (float*)(ws + (70ull << 20) + 4096);   // 4KB
  float* mu       = (float*)(ws + (71ull << 20));          // 64KB
  float* inv      = (float*)(ws + (72ull << 20));          // 64KB
  uint16_t* retr  = value;

  k_prep<<<8192 + 512 + 1024, 256, 0, stream>>>(x, Wv, Wo, lng, lnb, bo,
                                                xb, wv, wob, u, vb);
  k_gemm<0><<<(M_DIM / 256) * (D_DIM / 256), 512, 0, stream>>>(
      xb, wv, value, bv, nullptr, nullptr, nullptr, nullptr);
  k_passA<<<dim3(1, NCH, B_DIM), 256, 0, stream>>>(value, phases, pr, pi);
  k_passB<<<dim3(D_DIM / 256, B_DIM), 256, 0, stream>>>(pr, pi);
  k_passC<<<dim3(2, NCH, B_DIM), 256, 0, stream>>>(value, phases, pr, pi, retr);
  k_stats<<<M_DIM / 4, 256, 0, stream>>>(retr, mu, inv);
  k_gemm<1><<<(M_DIM / 256) * (D_DIM / 256), 512, 0, stream>>>(
      retr, wob, out, u, vb, mu, inv, xb);
}